// Round 4
// baseline (323.500 us; speedup 1.0000x reference)
//
#include <hip/hip_runtime.h>
#include <math.h>

#define N_ENT 64368
#define DIM 128
#define BATCH 512
#define SEQ 50
#define NPART 32

// ws float-index layout
#define WS_PART 0                   // NPART*BATCH floats (zeroed by kernel A)
#define WS_PICK (NPART * BATCH)     // 1 float: sum of picked scores
#define WS_CNT  (NPART * BATCH + 1) // 1 int: block arrival counter
#define WS_ABF_BYTES 131072         // bf16 u_emb at byte offset 128 KB

typedef __attribute__((ext_vector_type(8))) short short8;
typedef __attribute__((ext_vector_type(4))) float f32x4;

static __device__ __forceinline__ short f2bf(float f) {
  union { float f; unsigned u; } v;
  v.f = f;
  unsigned r = v.u + 0x7FFF + ((v.u >> 16) & 1);  // RNE
  return (short)(r >> 16);
}

// ---------------- kernel A: fused prep + u_emb (512 blocks x 256 thr)
__global__ __launch_bounds__(256) void fused_uemb(
    const float* __restrict__ emb, const float* __restrict__ W1,
    const float* __restrict__ W2, const float* __restrict__ q,
    const float* __restrict__ soft_bias, const int* __restrict__ seeds,
    float* __restrict__ ws, short* __restrict__ abf) {
  const int b = blockIdx.x;
  const int tid = threadIdx.x;
  __shared__ float v[SEQ][DIM];
  __shared__ float qw[2][DIM];
  __shared__ float att[SEQ];
  __shared__ int sidx[SEQ];
  __shared__ float qred[2];
  __shared__ float usum[2][DIM];
  __shared__ float qs_sh;

  // zero this block's ws_part slice; block 0 zeros picked + counter
  if (tid < NPART) ws[WS_PART + b * NPART + tid] = 0.f;
  if (b == 0 && tid == 0) {
    ws[WS_PICK] = 0.f;
    ((int*)ws)[WS_CNT] = 0;
  }
  if (tid < SEQ) sidx[tid] = seeds[b * SEQ + tid];

  // qW1/qW2 (redundant per block, L2-hot): m=tid>>7 picks matrix, d=tid&127
  {
    const int m = tid >> 7, d = tid & 127;
    const float* __restrict__ W = m ? W2 : W1;
    float acc = 0.f;
#pragma unroll 8
    for (int e = 0; e < DIM; ++e) acc += q[e] * W[e * DIM + d];
    qw[m][d] = acc;
    if (m == 0) {  // sum(q) from first two waves
      float s = q[d];
#pragma unroll
      for (int sh = 32; sh; sh >>= 1) s += __shfl_xor(s, sh, 64);
      if ((tid & 63) == 0) qred[tid >> 6] = s;
    }
  }
  __syncthreads();
  if (tid == 0) qs_sh = soft_bias[0] * (qred[0] + qred[1]);

  // stage v = emb[seed] + analytic PE (float4)
  const float kExpScale = -logf(10000.0f) / (float)DIM;
  for (int i = tid; i < SEQ * (DIM / 4); i += 256) {
    int l = i >> 5, c4 = i & 31;
    float4 e4 = reinterpret_cast<const float4*>(emb + (size_t)sidx[l] * DIM)[c4];
    int dd = c4 * 4;
    float div0 = __expf((float)dd * kExpScale);
    float div1 = __expf((float)(dd + 2) * kExpScale);
    float s0, c0, s1, c1;
    __sincosf((float)l * div0, &s0, &c0);
    __sincosf((float)l * div1, &s1, &c1);
    e4.x += s0 * 0.001f;
    e4.y += c0 * 0.001f;
    e4.z += s1 * 0.001f;
    e4.w += c1 * 0.001f;
    *reinterpret_cast<float4*>(&v[l][dd]) = e4;
  }
  __syncthreads();

  const int wave = tid >> 6, lane = tid & 63;
  // c = qW2 . vn + soft_bias*sum(q), redundant per wave
  float cs = qw[1][lane] * v[SEQ - 1][lane] + qw[1][64 + lane] * v[SEQ - 1][64 + lane];
#pragma unroll
  for (int m = 32; m; m >>= 1) cs += __shfl_xor(cs, m, 64);
  float c = cs + qs_sh;

  for (int l = wave; l < SEQ; l += 4) {
    float s = qw[0][lane] * v[l][lane] + qw[0][64 + lane] * v[l][64 + lane];
#pragma unroll
    for (int m = 32; m; m >>= 1) s += __shfl_xor(s, m, 64);
    if (lane == 0) att[l] = s + c;
  }
  __syncthreads();

  const int d = tid & 127, h = tid >> 7;
  float u = 0.f;
  for (int l = h * 25; l < h * 25 + 25; ++l) u += att[l] * v[l][d];
  usum[h][d] = u;
  __syncthreads();
  if (tid < 128) abf[b * DIM + tid] = f2bf(usum[0][tid] + usum[1][tid]);
}

// ---------------- kernel B: scores MFMA + exp partials + fused loss finale
__global__ __launch_bounds__(256) void scores_kernel(
    const float* __restrict__ emb, const float* __restrict__ out_bias,
    const short* __restrict__ abf, const int* __restrict__ labels,
    float* __restrict__ ws, float* __restrict__ out) {
  __shared__ float rowpart[BATCH][2];
  __shared__ int lbl[BATCH];
  __shared__ int islast_sh;
  __shared__ float wred[4];

  const int tid = threadIdx.x;
  const int lane = tid & 63;
  const int wid = tid >> 6;
  const int wr = wid >> 1;
  const int wc = wid & 1;
  const int lrow = lane & 15;
  const int lgrp = lane >> 4;
  const int colBase = blockIdx.x * 64;

  for (int i = tid; i < BATCH; i += 256) lbl[i] = labels[i];

  // B fragments: entity tile f32 -> bf16 (nontemporal: read exactly once grid-wide)
  short8 bfrag[2][4];
  float biasv[2];
  bool colok[2];
  int cols[2];
#pragma unroll
  for (int cf = 0; cf < 2; ++cf) {
    int col = colBase + wc * 32 + cf * 16 + lrow;
    cols[cf] = col;
    colok[cf] = (col < N_ENT);
    int e = colok[cf] ? col : (N_ENT - 1);
    biasv[cf] = colok[cf] ? out_bias[col] : 0.f;
#pragma unroll
    for (int ki = 0; ki < 4; ++ki) {
      const f32x4* p =
          reinterpret_cast<const f32x4*>(emb + (size_t)e * DIM + ki * 32 + lgrp * 8);
      f32x4 x0 = __builtin_nontemporal_load(p);
      f32x4 x1 = __builtin_nontemporal_load(p + 1);
      short8 f;
      f[0] = f2bf(x0[0]); f[1] = f2bf(x0[1]); f[2] = f2bf(x0[2]); f[3] = f2bf(x0[3]);
      f[4] = f2bf(x1[0]); f[5] = f2bf(x1[1]); f[6] = f2bf(x1[2]); f[7] = f2bf(x1[3]);
      bfrag[cf][ki] = f;
    }
  }
  __syncthreads();  // lbl ready

  float pickacc = 0.f;

  for (int c = 0; c < 8; ++c) {
    const int mBase = c * 64 + wr * 32;

    short8 afrag[2][4];
#pragma unroll
    for (int rf = 0; rf < 2; ++rf)
#pragma unroll
      for (int ki = 0; ki < 4; ++ki) {
        int row = mBase + rf * 16 + lrow;
        afrag[rf][ki] =
            *reinterpret_cast<const short8*>(abf + row * DIM + ki * 32 + lgrp * 8);
      }

    f32x4 acc[2][2];
#pragma unroll
    for (int rf = 0; rf < 2; ++rf)
#pragma unroll
      for (int cf = 0; cf < 2; ++cf)
#pragma unroll
        for (int r = 0; r < 4; ++r) acc[rf][cf][r] = 0.f;

#pragma unroll
    for (int ki = 0; ki < 4; ++ki)
#pragma unroll
      for (int rf = 0; rf < 2; ++rf)
#pragma unroll
        for (int cf = 0; cf < 2; ++cf)
          acc[rf][cf] = __builtin_amdgcn_mfma_f32_16x16x32_bf16(
              afrag[rf][ki], bfrag[cf][ki], acc[rf][cf], 0, 0, 0);

#pragma unroll
    for (int rf = 0; rf < 2; ++rf) {
      float pr[4] = {0.f, 0.f, 0.f, 0.f};
#pragma unroll
      for (int cf = 0; cf < 2; ++cf) {
        if (colok[cf]) {
#pragma unroll
          for (int r = 0; r < 4; ++r) {
            int row = mBase + rf * 16 + lgrp * 4 + r;
            float s = acc[rf][cf][r] + biasv[cf];
            __builtin_nontemporal_store(s, &out[(size_t)row * N_ENT + cols[cf]]);
            pr[r] += __expf(s);
            if (cols[cf] == lbl[row]) pickacc += s;  // picked score (<=512 matches grid-wide)
          }
        }
      }
#pragma unroll
      for (int r = 0; r < 4; ++r) {
#pragma unroll
        for (int m = 1; m < 16; m <<= 1) pr[r] += __shfl_xor(pr[r], m, 64);
      }
      if (lrow == 0) {
#pragma unroll
        for (int r = 0; r < 4; ++r)
          rowpart[mBase + rf * 16 + lgrp * 4 + r][wc] = pr[r];
      }
    }
  }
  if (pickacc != 0.f) atomicAdd(&ws[WS_PICK], pickacc);  // adding 0 is identity, skip is safe
  __syncthreads();

  const int slot = blockIdx.x & (NPART - 1);
  for (int r = tid; r < BATCH; r += 256)
    atomicAdd(&ws[WS_PART + slot * BATCH + r], rowpart[r][0] + rowpart[r][1]);

  // release: make this block's atomics visible, then count arrival
  __threadfence();
  __syncthreads();
  if (tid == 0) {
    int done = atomicAdd((int*)ws + WS_CNT, 1);
    islast_sh = (done == (int)gridDim.x - 1);
  }
  __syncthreads();

  if (islast_sh) {  // uniform per block
    __threadfence();  // acquire
    float lsum = 0.f;
    for (int r = tid; r < BATCH; r += 256) {
      float rs = 0.f;
#pragma unroll
      for (int p = 0; p < NPART; ++p)
        rs += __hip_atomic_load(&ws[WS_PART + p * BATCH + r], __ATOMIC_RELAXED,
                                __HIP_MEMORY_SCOPE_AGENT);
      lsum += __logf(rs);
    }
#pragma unroll
    for (int m = 32; m; m >>= 1) lsum += __shfl_xor(lsum, m, 64);
    if ((tid & 63) == 0) wred[tid >> 6] = lsum;
    __syncthreads();
    if (tid == 0) {
      float tot = wred[0] + wred[1] + wred[2] + wred[3];
      float picked = __hip_atomic_load(&ws[WS_PICK], __ATOMIC_RELAXED,
                                       __HIP_MEMORY_SCOPE_AGENT);
      out[(size_t)BATCH * N_ENT] = (tot - picked) / (float)BATCH;
    }
  }
}

extern "C" void kernel_launch(void* const* d_in, const int* in_sizes, int n_in,
                              void* d_out, int out_size, void* d_ws, size_t ws_size,
                              hipStream_t stream) {
  const float* entity_emb = (const float*)d_in[0];
  const float* W1 = (const float*)d_in[1];
  const float* W2 = (const float*)d_in[2];
  const float* q = (const float*)d_in[3];
  const float* soft_bias = (const float*)d_in[4];
  const float* out_bias = (const float*)d_in[5];
  const int* seeds = (const int*)d_in[6];
  const int* labels = (const int*)d_in[7];
  float* out = (float*)d_out;
  float* ws = (float*)d_ws;
  short* abf = (short*)((char*)d_ws + WS_ABF_BYTES);

  fused_uemb<<<BATCH, 256, 0, stream>>>(entity_emb, W1, W2, q, soft_bias, seeds,
                                        ws, abf);
  scores_kernel<<<(N_ENT + 63) / 64, 256, 0, stream>>>(entity_emb, out_bias, abf,
                                                       labels, ws, out);
}